// Round 9
// baseline (225.971 us; speedup 1.0000x reference)
//
#include <hip/hip_runtime.h>

typedef __attribute__((ext_vector_type(8))) short short8v;   // 8 bf16 (4 VGPRs)
typedef __attribute__((ext_vector_type(4))) float f32x4;     // MFMA accumulator

#define N_ROWS 8192
#define KSPLIT 768          // 3 x 256 (hi|lo|hi concatenation)
#define SEP 64
#define TDET 65.0f          // candidate-detection threshold on hi-only GEMM value
#define TEXACT 73.0f        // exact-bin boundary = TDET + guarded err bound
#define VTOL 5.5f           // |v_exact - dequant(v_hi)| guard
#define LIST_CAP 524288u
#define CAND_CAP 2048u      // per-block LDS candidate list (expected ~1.6/block)

// ---------- helpers ----------
__device__ inline unsigned f2ord(float x){
  unsigned u = __float_as_uint(x);
  return (u & 0x80000000u) ? ~u : (u | 0x80000000u);   // monotone f32 -> u32
}
__device__ inline float ord2f(unsigned u){
  unsigned b = (u & 0x80000000u) ? (u & 0x7fffffffu) : ~u;
  return __uint_as_float(b);
}
__device__ inline unsigned short bf16rn(float x){
  unsigned b = __float_as_uint(x);
  unsigned r = (b + 0x7fffu + ((b >> 16) & 1u)) >> 16;  // round-to-nearest-even
  return (unsigned short)r;
}
__device__ inline void gload16(const void* g, void* l){
  __builtin_amdgcn_global_load_lds((const __attribute__((address_space(1))) void*)g,
                                   (__attribute__((address_space(3))) void*)l, 16, 0, 0);
}
__device__ inline int bin_of(float v, float mnv, float interval){
  float r = (v - mnv) / interval;                       // true division, like ref
  int b = (int)floorf(r);
  return b < 0 ? 0 : (b > 63 ? 63 : b);
}

// ---------- K0: split f32 -> bf16 hi/lo, K-concatenated; block 0 inits control ----------
__global__ void split_kernel(const float* __restrict__ cur, const float* __restrict__ prev,
                             unsigned short* __restrict__ cur2, unsigned short* __restrict__ prev2,
                             unsigned* __restrict__ ctl){
  if (blockIdx.x == 0){
    // ctl: [0]=min(ord) [1]=max(ord) [2]=flag [3]=lcnt [4]=viol [5..68]=hist
    if (threadIdx.x == 0){
      ctl[0] = 0xFFFFFFFFu; ctl[1] = 0u; ctl[2] = 1u; ctl[3] = 0u; ctl[4] = 0u;
    }
    if (threadIdx.x < 64) ctl[5 + threadIdx.x] = 0u;
  }
  int g = blockIdx.x * blockDim.x + threadIdx.x;         // 0 .. 2*524288-1
  int isB = (g >= (N_ROWS * 256 / 4)) ? 1 : 0;
  int t = g - isB * (N_ROWS * 256 / 4);
  const float4 v = ((const float4*)(isB ? prev : cur))[t];
  int row = t >> 6;                                      // 64 float4 per 256-col row
  int col = (t & 63) << 2;
  float xs[4] = {v.x, v.y, v.z, v.w};
  unsigned short h[4], l[4];
  #pragma unroll
  for (int j = 0; j < 4; ++j){
    unsigned short hb = bf16rn(xs[j]);
    float hf = __uint_as_float(((unsigned)hb) << 16);
    h[j] = hb;
    l[j] = bf16rn(xs[j] - hf);                           // residual capture
  }
  unsigned short* dst = isB ? prev2 : cur2;
  size_t base = (size_t)row * KSPLIT + col;
  uint2 hw, lw;
  hw.x = (unsigned)h[0] | ((unsigned)h[1] << 16); hw.y = (unsigned)h[2] | ((unsigned)h[3] << 16);
  lw.x = (unsigned)l[0] | ((unsigned)l[1] << 16); lw.y = (unsigned)l[2] | ((unsigned)l[3] << 16);
  *(uint2*)(dst + base) = hw;
  if (!isB){
    *(uint2*)(dst + base + 256) = lw;
    *(uint2*)(dst + base + 512) = hw;
  } else {
    *(uint2*)(dst + base + 256) = hw;
    *(uint2*)(dst + base + 512) = lw;
  }
}

// ---------- detection GEMM: 128x128, 4 waves (2x2), 2-phase dbuf prefetch ----------
// hi-only (K=256 = first 8 K-steps of hi|lo|hi). Epilogue: candidate spill to LDS,
// block-aggregated global reservation, in-kernel exact f32 recompute + guards.
__global__ __launch_bounds__(256) void gemm_det(const unsigned short* __restrict__ A2,
                                                const unsigned short* __restrict__ B2,
                                                const float* __restrict__ cur,
                                                const float* __restrict__ prev,
                                                unsigned* __restrict__ idxq,
                                                float* __restrict__ vex,
                                                unsigned* __restrict__ lcnt,
                                                unsigned* __restrict__ mm,
                                                unsigned* __restrict__ viol){
  __shared__ unsigned short Ab[2][128 * 32];             // 16 KB
  __shared__ unsigned short Bb[2][128 * 32];             // 16 KB (32 KB total)
  __shared__ unsigned bcnt, gbase, ccap;

  const int tid  = threadIdx.x;
  const int lane = tid & 63;
  const int wave = tid >> 6;
  // XCD-aware bijective swizzle: 4096 blocks = 8 XCDs x 512
  const int swz = ((blockIdx.x & 7) << 9) | (blockIdx.x >> 3);
  const int bm = swz >> 6;
  const int bn = swz & 63;
  const int wr = wave >> 1, wc = wave & 1;

  if (tid == 0) bcnt = 0u;                               // visible after first barrier

  const size_t aBase = (size_t)bm * 128 * KSPLIT;
  const size_t bBase = (size_t)bn * 128 * KSPLIT;
  const int id0 = tid, id1 = tid + 256;                  // 512 x 16B chunks per tile
  const size_t aOff0 = aBase + (size_t)(id0 >> 2) * KSPLIT + (id0 & 3) * 8;
  const size_t aOff1 = aBase + (size_t)(id1 >> 2) * KSPLIT + (id1 & 3) * 8;
  const size_t bOff0 = bBase + (size_t)(id0 >> 2) * KSPLIT + (id0 & 3) * 8;
  const size_t bOff1 = bBase + (size_t)(id1 >> 2) * KSPLIT + (id1 & 3) * 8;

  f32x4 acc[4][4];
  #pragma unroll
  for (int m = 0; m < 4; ++m)
    #pragma unroll
    for (int n = 0; n < 4; ++n)
      acc[m][n] = (f32x4){0.f, 0.f, 0.f, 0.f};

  const int rsel = lane & 15;
  const int ksel = (lane >> 4) * 8;

  auto STAGE = [&](int ks, int b){
    const int k0 = ks * 32;
    gload16(A2 + aOff0 + k0, &Ab[b][id0 * 8]);
    gload16(A2 + aOff1 + k0, &Ab[b][id1 * 8]);
    gload16(B2 + bOff0 + k0, &Bb[b][id0 * 8]);
    gload16(B2 + bOff1 + k0, &Bb[b][id1 * 8]);
  };
  auto COMPUTE = [&](int b){
    short8v a[4], bv[4];
    #pragma unroll
    for (int m = 0; m < 4; ++m)
      a[m] = *(const short8v*)(&Ab[b][(wr * 64 + m * 16 + rsel) * 32 + ksel]);
    #pragma unroll
    for (int n = 0; n < 4; ++n)
      bv[n] = *(const short8v*)(&Bb[b][(wc * 64 + n * 16 + rsel) * 32 + ksel]);
    #pragma unroll
    for (int m = 0; m < 4; ++m)
      #pragma unroll
      for (int n = 0; n < 4; ++n)
        acc[m][n] = __builtin_amdgcn_mfma_f32_16x16x32_bf16(a[m], bv[n], acc[m][n], 0, 0, 0);
  };

  STAGE(0, 0);
  __syncthreads();                                       // compiler drains vmcnt(0) here
  for (int ks = 0; ks < 8; ++ks){
    if (ks < 7) STAGE(ks + 1, (ks + 1) & 1);             // prefetch into other buffer
    COMPUTE(ks & 1);                                     // MFMA overlaps in-flight loads
    __syncthreads();                                     // drain prefetch + join readers
  }

  // ---- epilogue: candidate spill into LDS (overlay on Ab; dead after last barrier) ----
  unsigned* cand = (unsigned*)Ab;                        // CAND_CAP u32 slots

  unsigned long long mask = 0ull;
  #pragma unroll
  for (int m = 0; m < 4; ++m)
    #pragma unroll
    for (int n = 0; n < 4; ++n)
      #pragma unroll
      for (int q = 0; q < 4; ++q)
        if (fabsf(acc[m][n][q]) > TDET)
          mask |= (1ull << ((m * 4 + n) * 4 + q));
  int cnt = __popcll(mask);
  int pre = cnt;                                         // inclusive prefix over 64 lanes
  #pragma unroll
  for (int off = 1; off < 64; off <<= 1){
    int t = __shfl_up(pre, off);
    if (lane >= off) pre += t;
  }
  int tot = __shfl(pre, 63);                             // wave total
  unsigned wbase = 0;
  if (lane == 63 && tot > 0) wbase = atomicAdd(&bcnt, (unsigned)tot);  // LDS atomic
  wbase = __shfl((int)wbase, 63);
  if (mask){
    unsigned kk = wbase + (unsigned)(pre - cnt);
    #pragma unroll
    for (int m = 0; m < 4; ++m)
      #pragma unroll
      for (int n = 0; n < 4; ++n)
        #pragma unroll
        for (int q = 0; q < 4; ++q){
          int b = (m * 4 + n) * 4 + q;
          if ((mask >> b) & 1ull){
            float v = acc[m][n][q];
            // D layout (m89/m91-verified): row=(lane>>4)*4+q, col=lane&15
            int i = bm * 128 + wr * 64 + m * 16 + ((lane >> 4) << 2) + q;
            int j = bn * 128 + wc * 64 + n * 16 + (lane & 15);
            int e = (int)((v + 144.0f) * (1.0f / 4.5f));   // 6-bit quant, step 4.5
            e = e < 0 ? 0 : (e > 63 ? 63 : e);
            if (kk < CAND_CAP)
              cand[kk] = ((unsigned)e << 26) | ((unsigned)i << 13) | (unsigned)j;
            ++kk;
          }
        }
  }
  __syncthreads();                                       // cand[] + bcnt final
  if (tid == 0){
    unsigned c = bcnt;
    unsigned cc = c > CAND_CAP ? CAND_CAP : c;
    if (c > CAND_CAP) atomicAdd(viol, 1u);               // lost candidates -> exact fallback
    gbase = cc ? atomicAdd(lcnt, cc) : 0u;               // ONE global atomic per block
    ccap = cc;
  }
  __syncthreads();

  // ---- in-kernel exact f32 recompute (one wave per candidate, round-robin) ----
  const unsigned cc = ccap, gb = gbase;
  float wmn = 3.4e38f, wmx = -3.4e38f;
  bool any = false;
  for (unsigned c = (unsigned)wave; c < cc; c += 4u){
    unsigned u = cand[c];
    int i = (int)((u >> 13) & 8191u), j = (int)(u & 8191u);
    float4 a = ((const float4*)cur)[i * 64 + lane];      // wave reads 1KB contiguous
    float4 b = ((const float4*)prev)[j * 64 + lane];
    float s = a.x * b.x + a.y * b.y + a.z * b.z + a.w * b.w;
    #pragma unroll
    for (int off = 32; off; off >>= 1) s += __shfl_xor(s, off);
    unsigned gi = gb + c;
    if (lane == 0 && gi < LIST_CAP){
      vex[gi]  = s;
      idxq[gi] = u;
      float dq = ((float)(u >> 26) + 0.5f) * 4.5f - 144.0f;
      if (fabsf(s - dq) > VTOL) atomicAdd(viol, 1u);     // layout/index guard
    }
    wmn = fminf(wmn, s); wmx = fmaxf(wmx, s);
    any = true;
  }
  if (lane == 0 && any){
    atomicMin(mm + 0, f2ord(wmn));
    atomicMax(mm + 1, f2ord(wmx));
  }
}

// ---------- fallback GEMM (exact, verified r1-r6 structure): 128x128, K=768 ----------
// EPI 0: min/max only; EPI 2: exact 64-bin histogram. Both no-op when flag==0.
template<int EPI>
__global__ __launch_bounds__(256) void gemm_kernel(const unsigned short* __restrict__ A2,
                                                   const unsigned short* __restrict__ B2,
                                                   unsigned* __restrict__ mm,
                                                   unsigned* __restrict__ hist,
                                                   const unsigned* __restrict__ flag){
  if (flag[0] == 0u) return;                             // analytic path succeeded: no-op
  __shared__ unsigned short As[128 * 32];
  __shared__ unsigned short Bs[128 * 32];

  const int tid  = threadIdx.x;
  const int lane = tid & 63;
  const int wave = tid >> 6;
  const int swz = ((blockIdx.x & 7) << 9) | (blockIdx.x >> 3);
  const int bm = swz >> 6;
  const int bn = swz & 63;
  const int wr = wave >> 1, wc = wave & 1;

  const size_t aBase = (size_t)bm * 128 * KSPLIT;
  const size_t bBase = (size_t)bn * 128 * KSPLIT;
  const int id0 = tid, id1 = tid + 256;
  const size_t aOff0 = aBase + (size_t)(id0 >> 2) * KSPLIT + (id0 & 3) * 8;
  const size_t aOff1 = aBase + (size_t)(id1 >> 2) * KSPLIT + (id1 & 3) * 8;
  const size_t bOff0 = bBase + (size_t)(id0 >> 2) * KSPLIT + (id0 & 3) * 8;
  const size_t bOff1 = bBase + (size_t)(id1 >> 2) * KSPLIT + (id1 & 3) * 8;

  f32x4 acc[4][4];
  #pragma unroll
  for (int m = 0; m < 4; ++m)
    #pragma unroll
    for (int n = 0; n < 4; ++n)
      acc[m][n] = (f32x4){0.f, 0.f, 0.f, 0.f};

  const int rsel = lane & 15;
  const int ksel = (lane >> 4) * 8;

  for (int ks = 0; ks < 24; ++ks){
    const int k0 = ks * 32;
    gload16(A2 + aOff0 + k0, As + id0 * 8);
    gload16(A2 + aOff1 + k0, As + id1 * 8);
    gload16(B2 + bOff0 + k0, Bs + id0 * 8);
    gload16(B2 + bOff1 + k0, Bs + id1 * 8);
    __syncthreads();
    short8v a[4], b[4];
    #pragma unroll
    for (int m = 0; m < 4; ++m)
      a[m] = *(const short8v*)(As + (wr * 64 + m * 16 + rsel) * 32 + ksel);
    #pragma unroll
    for (int n = 0; n < 4; ++n)
      b[n] = *(const short8v*)(Bs + (wc * 64 + n * 16 + rsel) * 32 + ksel);
    #pragma unroll
    for (int m = 0; m < 4; ++m)
      #pragma unroll
      for (int n = 0; n < 4; ++n)
        acc[m][n] = __builtin_amdgcn_mfma_f32_16x16x32_bf16(a[m], b[n], acc[m][n], 0, 0, 0);
    __syncthreads();
  }

  float*    red = (float*)As;                            // epilogue overlays (As dead)
  unsigned* lh  = (unsigned*)((char*)As + 64);

  if (EPI == 0){
    float mn = 3.4e38f, mx = -3.4e38f;
    #pragma unroll
    for (int m = 0; m < 4; ++m)
      #pragma unroll
      for (int n = 0; n < 4; ++n)
        #pragma unroll
        for (int q = 0; q < 4; ++q){
          float v = acc[m][n][q];
          mn = fminf(mn, v); mx = fmaxf(mx, v);
        }
    #pragma unroll
    for (int off = 32; off; off >>= 1){
      mn = fminf(mn, __shfl_xor(mn, off));
      mx = fmaxf(mx, __shfl_xor(mx, off));
    }
    if (lane == 0){ red[wave] = mn; red[4 + wave] = mx; }
    __syncthreads();
    if (tid == 0){
      mn = fminf(fminf(red[0], red[1]), fminf(red[2], red[3]));
      mx = fmaxf(fmaxf(red[4], red[5]), fmaxf(red[6], red[7]));
      atomicMin(mm + 0, f2ord(mn));
      atomicMax(mm + 1, f2ord(mx));
    }
  }
  if (EPI == 2){
    if (tid < SEP) lh[tid] = 0u;
    __syncthreads();
    const float mnv = ord2f(mm[0]);
    const float mxv = ord2f(mm[1]);
    const float interval = (mxv - mnv) / 64.0f;
    #pragma unroll
    for (int m = 0; m < 4; ++m)
      #pragma unroll
      for (int n = 0; n < 4; ++n)
        #pragma unroll
        for (int q = 0; q < 4; ++q)
          atomicAdd(&lh[bin_of(acc[m][n][q], mnv, interval)], 1u);
    __syncthreads();
    if (tid < SEP){ unsigned c = lh[tid]; if (c) atomicAdd(hist + tid, c); }
  }
}

// ---------- tail histogram + analytic finalize (1 block). flag: 0 = done ----------
__global__ __launch_bounds__(256) void finalize2_kernel(const unsigned* __restrict__ mm,
                                                        const unsigned* __restrict__ lcnt,
                                                        const unsigned* __restrict__ viol,
                                                        const float* __restrict__ vex,
                                                        const float* __restrict__ W,
                                                        unsigned* __restrict__ flag,
                                                        float* __restrict__ out){
  __shared__ unsigned h[SEP];
  __shared__ unsigned okf;
  const int tid = threadIdx.x;
  if (tid < SEP) h[tid] = 0u;
  __syncthreads();
  const float mnv = ord2f(mm[0]);
  const float mxv = ord2f(mm[1]);
  const float interval = (mxv - mnv) / 64.0f;
  const unsigned cnt = lcnt[0];
  const unsigned n = cnt > LIST_CAP ? LIST_CAP : cnt;
  for (unsigned i = tid; i < n; i += 256u)
    atomicAdd(&h[bin_of(vex[i], mnv, interval)], 1u);
  __syncthreads();
  if (tid == 0){
    // Monotone binning: bins strictly outside [bin(-TEXACT), bin(TEXACT)] hold ONLY
    // candidate values (guarded model-error bound), so their counts here are exact.
    const int bLO = bin_of(-TEXACT, mnv, interval);
    const int bHI = bin_of( TEXACT, mnv, interval);
    bool ok = (cnt <= LIST_CAP) && (viol[0] == 0u) && (bLO >= 3) && (bHI <= 60) && (bLO < bHI)
              && (h[bLO - 1] >= 30u) && (h[bHI + 1] >= 30u);
    okf = ok ? 1u : 0u;
    if (ok) flag[0] = 0u;                                // analytic path done
  }
  __syncthreads();
  if (!okf) return;                                      // flag stays 1 -> exact fallback
  if (tid < 64){
    const int bLO = bin_of(-TEXACT, mnv, interval);
    const int bHI = bin_of( TEXACT, mnv, interval);
    float beta;
    if (tid < bLO || tid > bHI) beta = 1.f / (1.f + expf(-(float)h[tid]));
    else beta = 1.0f;                                    // count >= 30 -> f32 sigmoid == 1.0f
    float p = beta * W[tid];
    #pragma unroll
    for (int off = 32; off; off >>= 1) p += __shfl_down(p, off);
    if (tid == 0) out[0] = 1.f / (1.f + expf(-p));
  }
}

// ---------- fallback finalize: out = sigmoid( sum_j sigmoid(count_j) * W_j ) ----------
__global__ void fin_kernel(const unsigned* __restrict__ hist, const float* __restrict__ W,
                           const unsigned* __restrict__ flag, float* __restrict__ out){
  if (flag[0] == 0u) return;                             // finalize2 already wrote out
  int j = threadIdx.x;                                   // 64 threads = 1 wave
  float beta = 1.f / (1.f + expf(-(float)hist[j]));
  float p = beta * W[j];
  #pragma unroll
  for (int off = 32; off; off >>= 1) p += __shfl_down(p, off);
  if (j == 0) out[0] = 1.f / (1.f + expf(-p));
}

extern "C" void kernel_launch(void* const* d_in, const int* in_sizes, int n_in,
                              void* d_out, int out_size, void* d_ws, size_t ws_size,
                              hipStream_t stream){
  const float* cur  = (const float*)d_in[0];
  const float* prev = (const float*)d_in[1];
  const float* W    = (const float*)d_in[2];
  float* out = (float*)d_out;
  char* ws = (char*)d_ws;

  // ws layout
  unsigned short* cur2  = (unsigned short*)ws;                 // 12,582,912 B
  unsigned short* prev2 = (unsigned short*)(ws + 12582912);    // 12,582,912 B -> 25,165,824
  unsigned* ctl   = (unsigned*)(ws + 25165824);                // control block
  unsigned* mm    = ctl + 0;                                   // [min,max] ordered-u32
  unsigned* flag  = ctl + 2;
  unsigned* lcnt  = ctl + 3;
  unsigned* viol  = ctl + 4;
  unsigned* hist  = ctl + 5;                                   // 64 x u32 (fallback)
  unsigned* idxq  = (unsigned*)(ws + 25166592);                // 2 MiB packed candidates
  float*    vex   = (float*)(ws + 27263744);                   // 2 MiB exact values
  const size_t NEED_NEW = 29360896;                            // known to fit (r5-r7 ran)

  split_kernel<<<4096, 256, 0, stream>>>(cur, prev, cur2, prev2, ctl);

  if (ws_size >= NEED_NEW){
    // hi-only dbuf GEMM + fused candidate spill/recompute; then hist+finalize
    gemm_det<<<4096, 256, 0, stream>>>(cur2, prev2, cur, prev, idxq, vex, lcnt, mm, viol);
    finalize2_kernel<<<1, 256, 0, stream>>>(mm, lcnt, viol, vex, W, flag, out);
    // guarded exact fallback (no-ops when flag == 0)
    gemm_kernel<0><<<4096, 256, 0, stream>>>(cur2, prev2, mm, hist, flag);
    gemm_kernel<2><<<4096, 256, 0, stream>>>(cur2, prev2, mm, hist, flag);
    fin_kernel<<<1, 64, 0, stream>>>(hist, W, flag, out);
  } else {
    // exact 2-pass path (flag stays 1 -> EPI0 + EPI2 + fin run fully)
    gemm_kernel<0><<<4096, 256, 0, stream>>>(cur2, prev2, mm, hist, flag);
    gemm_kernel<2><<<4096, 256, 0, stream>>>(cur2, prev2, mm, hist, flag);
    fin_kernel<<<1, 64, 0, stream>>>(hist, W, flag, out);
  }
}

// Round 10
// 222.066 us; speedup vs baseline: 1.0176x; 1.0176x over previous
//
#include <hip/hip_runtime.h>

typedef __attribute__((ext_vector_type(8))) short short8v;   // 8 bf16 (4 VGPRs)
typedef __attribute__((ext_vector_type(4))) float f32x4;     // MFMA accumulator

#define N_ROWS 8192
#define KSPLIT 768          // 3 x 256 (hi|lo|hi concatenation)
#define SEP 64
#define TDET 65.0f          // candidate-detection threshold on hi-only GEMM value
#define TEXACT 73.0f        // exact-bin boundary = TDET + guarded err bound
#define VTOL 5.5f           // |v_exact - dequant(v_hi)| guard
#define LIST_CAP 524288u
#define CAND_CAP 2048u      // per-block LDS candidate list (expected ~1.6/block)

// ---------- helpers ----------
__device__ inline unsigned f2ord(float x){
  unsigned u = __float_as_uint(x);
  return (u & 0x80000000u) ? ~u : (u | 0x80000000u);   // monotone f32 -> u32
}
__device__ inline float ord2f(unsigned u){
  unsigned b = (u & 0x80000000u) ? (u & 0x7fffffffu) : ~u;
  return __uint_as_float(b);
}
__device__ inline unsigned short bf16rn(float x){
  unsigned b = __float_as_uint(x);
  unsigned r = (b + 0x7fffu + ((b >> 16) & 1u)) >> 16;  // round-to-nearest-even
  return (unsigned short)r;
}
__device__ inline void gload16(const void* g, void* l){
  __builtin_amdgcn_global_load_lds((const __attribute__((address_space(1))) void*)g,
                                   (__attribute__((address_space(3))) void*)l, 16, 0, 0);
}
__device__ inline int bin_of(float v, float mnv, float interval){
  float r = (v - mnv) / interval;                       // true division, like ref
  int b = (int)floorf(r);
  return b < 0 ? 0 : (b > 63 ? 63 : b);
}

// ---------- K0: split f32 -> bf16 hi/lo, K-concatenated; block 0 inits control ----------
__global__ void split_kernel(const float* __restrict__ cur, const float* __restrict__ prev,
                             unsigned short* __restrict__ cur2, unsigned short* __restrict__ prev2,
                             unsigned* __restrict__ ctl){
  if (blockIdx.x == 0){
    // ctl: [0]=min(ord) [1]=max(ord) [2]=flag [3]=lcnt [4]=viol [5..68]=hist
    if (threadIdx.x == 0){
      ctl[0] = 0xFFFFFFFFu; ctl[1] = 0u; ctl[2] = 1u; ctl[3] = 0u; ctl[4] = 0u;
    }
    if (threadIdx.x < 64) ctl[5 + threadIdx.x] = 0u;
  }
  int g = blockIdx.x * blockDim.x + threadIdx.x;         // 0 .. 2*524288-1
  int isB = (g >= (N_ROWS * 256 / 4)) ? 1 : 0;
  int t = g - isB * (N_ROWS * 256 / 4);
  const float4 v = ((const float4*)(isB ? prev : cur))[t];
  int row = t >> 6;                                      // 64 float4 per 256-col row
  int col = (t & 63) << 2;
  float xs[4] = {v.x, v.y, v.z, v.w};
  unsigned short h[4], l[4];
  #pragma unroll
  for (int j = 0; j < 4; ++j){
    unsigned short hb = bf16rn(xs[j]);
    float hf = __uint_as_float(((unsigned)hb) << 16);
    h[j] = hb;
    l[j] = bf16rn(xs[j] - hf);                           // residual capture
  }
  unsigned short* dst = isB ? prev2 : cur2;
  size_t base = (size_t)row * KSPLIT + col;
  uint2 hw, lw;
  hw.x = (unsigned)h[0] | ((unsigned)h[1] << 16); hw.y = (unsigned)h[2] | ((unsigned)h[3] << 16);
  lw.x = (unsigned)l[0] | ((unsigned)l[1] << 16); lw.y = (unsigned)l[2] | ((unsigned)l[3] << 16);
  *(uint2*)(dst + base) = hw;
  if (!isB){
    *(uint2*)(dst + base + 256) = lw;
    *(uint2*)(dst + base + 512) = hw;
  } else {
    *(uint2*)(dst + base + 256) = hw;
    *(uint2*)(dst + base + 512) = lw;
  }
}

// ---------- detection GEMM: 128x128, 4 waves (2x2), single-buffer 2-barrier loop ----------
// (r6-verified 74us structure). hi-only (K=256 = first 8 K-steps of hi|lo|hi).
// Epilogue: candidate spill to LDS, block-aggregated reservation, fused exact recompute.
__global__ __launch_bounds__(256) void gemm_det(const unsigned short* __restrict__ A2,
                                                const unsigned short* __restrict__ B2,
                                                const float* __restrict__ cur,
                                                const float* __restrict__ prev,
                                                unsigned* __restrict__ idxq,
                                                float* __restrict__ vex,
                                                unsigned* __restrict__ lcnt,
                                                unsigned* __restrict__ mm,
                                                unsigned* __restrict__ viol){
  __shared__ unsigned short As[128 * 32];                // 8 KB
  __shared__ unsigned short Bs[128 * 32];                // 8 KB
  __shared__ unsigned bcnt, gbase, ccap;

  const int tid  = threadIdx.x;
  const int lane = tid & 63;
  const int wave = tid >> 6;
  // XCD-aware bijective swizzle: 4096 blocks = 8 XCDs x 512
  const int swz = ((blockIdx.x & 7) << 9) | (blockIdx.x >> 3);
  const int bm = swz >> 6;
  const int bn = swz & 63;
  const int wr = wave >> 1, wc = wave & 1;

  if (tid == 0) bcnt = 0u;                               // covered by first K-loop barrier

  const size_t aBase = (size_t)bm * 128 * KSPLIT;
  const size_t bBase = (size_t)bn * 128 * KSPLIT;
  const int id0 = tid, id1 = tid + 256;                  // 512 x 16B chunks per tile
  const size_t aOff0 = aBase + (size_t)(id0 >> 2) * KSPLIT + (id0 & 3) * 8;
  const size_t aOff1 = aBase + (size_t)(id1 >> 2) * KSPLIT + (id1 & 3) * 8;
  const size_t bOff0 = bBase + (size_t)(id0 >> 2) * KSPLIT + (id0 & 3) * 8;
  const size_t bOff1 = bBase + (size_t)(id1 >> 2) * KSPLIT + (id1 & 3) * 8;

  f32x4 acc[4][4];
  #pragma unroll
  for (int m = 0; m < 4; ++m)
    #pragma unroll
    for (int n = 0; n < 4; ++n)
      acc[m][n] = (f32x4){0.f, 0.f, 0.f, 0.f};

  const int rsel = lane & 15;
  const int ksel = (lane >> 4) * 8;

  for (int ks = 0; ks < 8; ++ks){
    const int k0 = ks * 32;
    gload16(A2 + aOff0 + k0, As + id0 * 8);
    gload16(A2 + aOff1 + k0, As + id1 * 8);
    gload16(B2 + bOff0 + k0, Bs + id0 * 8);
    gload16(B2 + bOff1 + k0, Bs + id1 * 8);
    __syncthreads();
    short8v a[4], b[4];
    #pragma unroll
    for (int m = 0; m < 4; ++m)
      a[m] = *(const short8v*)(As + (wr * 64 + m * 16 + rsel) * 32 + ksel);
    #pragma unroll
    for (int n = 0; n < 4; ++n)
      b[n] = *(const short8v*)(Bs + (wc * 64 + n * 16 + rsel) * 32 + ksel);
    #pragma unroll
    for (int m = 0; m < 4; ++m)
      #pragma unroll
      for (int n = 0; n < 4; ++n)
        acc[m][n] = __builtin_amdgcn_mfma_f32_16x16x32_bf16(a[m], b[n], acc[m][n], 0, 0, 0);
    __syncthreads();
  }

  // ---- epilogue: candidate spill into LDS (overlay on As; dead after last barrier) ----
  unsigned* cand = (unsigned*)As;                        // CAND_CAP u32 slots

  unsigned long long mask = 0ull;
  #pragma unroll
  for (int m = 0; m < 4; ++m)
    #pragma unroll
    for (int n = 0; n < 4; ++n)
      #pragma unroll
      for (int q = 0; q < 4; ++q)
        if (fabsf(acc[m][n][q]) > TDET)
          mask |= (1ull << ((m * 4 + n) * 4 + q));
  int cnt = __popcll(mask);
  int pre = cnt;                                         // inclusive prefix over 64 lanes
  #pragma unroll
  for (int off = 1; off < 64; off <<= 1){
    int t = __shfl_up(pre, off);
    if (lane >= off) pre += t;
  }
  int tot = __shfl(pre, 63);                             // wave total
  unsigned wbase = 0;
  if (lane == 63 && tot > 0) wbase = atomicAdd(&bcnt, (unsigned)tot);  // LDS atomic
  wbase = __shfl((int)wbase, 63);
  if (mask){
    unsigned kk = wbase + (unsigned)(pre - cnt);
    #pragma unroll
    for (int m = 0; m < 4; ++m)
      #pragma unroll
      for (int n = 0; n < 4; ++n)
        #pragma unroll
        for (int q = 0; q < 4; ++q){
          int b = (m * 4 + n) * 4 + q;
          if ((mask >> b) & 1ull){
            float v = acc[m][n][q];
            // D layout (m89/m91-verified): row=(lane>>4)*4+q, col=lane&15
            int i = bm * 128 + wr * 64 + m * 16 + ((lane >> 4) << 2) + q;
            int j = bn * 128 + wc * 64 + n * 16 + (lane & 15);
            int e = (int)((v + 144.0f) * (1.0f / 4.5f));   // 6-bit quant, step 4.5
            e = e < 0 ? 0 : (e > 63 ? 63 : e);
            if (kk < CAND_CAP)
              cand[kk] = ((unsigned)e << 26) | ((unsigned)i << 13) | (unsigned)j;
            ++kk;
          }
        }
  }
  __syncthreads();                                       // cand[] + bcnt final
  if (tid == 0){
    unsigned c = bcnt;
    unsigned cc = c > CAND_CAP ? CAND_CAP : c;
    if (c > CAND_CAP) atomicAdd(viol, 1u);               // lost candidates -> exact fallback
    gbase = cc ? atomicAdd(lcnt, cc) : 0u;               // ONE global atomic per block
    ccap = cc;
  }
  __syncthreads();

  // ---- in-kernel exact f32 recompute (one wave per candidate, round-robin) ----
  const unsigned cc = ccap, gb = gbase;
  float wmn = 3.4e38f, wmx = -3.4e38f;
  bool any = false;
  for (unsigned c = (unsigned)wave; c < cc; c += 4u){
    unsigned u = cand[c];
    int i = (int)((u >> 13) & 8191u), j = (int)(u & 8191u);
    float4 a = ((const float4*)cur)[i * 64 + lane];      // wave reads 1KB contiguous
    float4 b = ((const float4*)prev)[j * 64 + lane];
    float s = a.x * b.x + a.y * b.y + a.z * b.z + a.w * b.w;
    #pragma unroll
    for (int off = 32; off; off >>= 1) s += __shfl_xor(s, off);
    unsigned gi = gb + c;
    if (lane == 0 && gi < LIST_CAP){
      vex[gi]  = s;
      idxq[gi] = u;
      float dq = ((float)(u >> 26) + 0.5f) * 4.5f - 144.0f;
      if (fabsf(s - dq) > VTOL) atomicAdd(viol, 1u);     // layout/index guard
    }
    wmn = fminf(wmn, s); wmx = fmaxf(wmx, s);
    any = true;
  }
  if (lane == 0 && any){
    atomicMin(mm + 0, f2ord(wmn));
    atomicMax(mm + 1, f2ord(wmx));
  }
}

// ---------- fallback GEMM (exact, verified r1-r6 structure): 128x128, K=768 ----------
// EPI 0: min/max only; EPI 2: exact 64-bin histogram. Both no-op when flag==0.
template<int EPI>
__global__ __launch_bounds__(256) void gemm_kernel(const unsigned short* __restrict__ A2,
                                                   const unsigned short* __restrict__ B2,
                                                   unsigned* __restrict__ mm,
                                                   unsigned* __restrict__ hist,
                                                   const unsigned* __restrict__ flag){
  if (flag[0] == 0u) return;                             // analytic path succeeded: no-op
  __shared__ unsigned short As[128 * 32];
  __shared__ unsigned short Bs[128 * 32];

  const int tid  = threadIdx.x;
  const int lane = tid & 63;
  const int wave = tid >> 6;
  const int swz = ((blockIdx.x & 7) << 9) | (blockIdx.x >> 3);
  const int bm = swz >> 6;
  const int bn = swz & 63;
  const int wr = wave >> 1, wc = wave & 1;

  const size_t aBase = (size_t)bm * 128 * KSPLIT;
  const size_t bBase = (size_t)bn * 128 * KSPLIT;
  const int id0 = tid, id1 = tid + 256;
  const size_t aOff0 = aBase + (size_t)(id0 >> 2) * KSPLIT + (id0 & 3) * 8;
  const size_t aOff1 = aBase + (size_t)(id1 >> 2) * KSPLIT + (id1 & 3) * 8;
  const size_t bOff0 = bBase + (size_t)(id0 >> 2) * KSPLIT + (id0 & 3) * 8;
  const size_t bOff1 = bBase + (size_t)(id1 >> 2) * KSPLIT + (id1 & 3) * 8;

  f32x4 acc[4][4];
  #pragma unroll
  for (int m = 0; m < 4; ++m)
    #pragma unroll
    for (int n = 0; n < 4; ++n)
      acc[m][n] = (f32x4){0.f, 0.f, 0.f, 0.f};

  const int rsel = lane & 15;
  const int ksel = (lane >> 4) * 8;

  for (int ks = 0; ks < 24; ++ks){
    const int k0 = ks * 32;
    gload16(A2 + aOff0 + k0, As + id0 * 8);
    gload16(A2 + aOff1 + k0, As + id1 * 8);
    gload16(B2 + bOff0 + k0, Bs + id0 * 8);
    gload16(B2 + bOff1 + k0, Bs + id1 * 8);
    __syncthreads();
    short8v a[4], b[4];
    #pragma unroll
    for (int m = 0; m < 4; ++m)
      a[m] = *(const short8v*)(As + (wr * 64 + m * 16 + rsel) * 32 + ksel);
    #pragma unroll
    for (int n = 0; n < 4; ++n)
      b[n] = *(const short8v*)(Bs + (wc * 64 + n * 16 + rsel) * 32 + ksel);
    #pragma unroll
    for (int m = 0; m < 4; ++m)
      #pragma unroll
      for (int n = 0; n < 4; ++n)
        acc[m][n] = __builtin_amdgcn_mfma_f32_16x16x32_bf16(a[m], b[n], acc[m][n], 0, 0, 0);
    __syncthreads();
  }

  float*    red = (float*)As;                            // epilogue overlays (As dead)
  unsigned* lh  = (unsigned*)((char*)As + 64);

  if (EPI == 0){
    float mn = 3.4e38f, mx = -3.4e38f;
    #pragma unroll
    for (int m = 0; m < 4; ++m)
      #pragma unroll
      for (int n = 0; n < 4; ++n)
        #pragma unroll
        for (int q = 0; q < 4; ++q){
          float v = acc[m][n][q];
          mn = fminf(mn, v); mx = fmaxf(mx, v);
        }
    #pragma unroll
    for (int off = 32; off; off >>= 1){
      mn = fminf(mn, __shfl_xor(mn, off));
      mx = fmaxf(mx, __shfl_xor(mx, off));
    }
    if (lane == 0){ red[wave] = mn; red[4 + wave] = mx; }
    __syncthreads();
    if (tid == 0){
      mn = fminf(fminf(red[0], red[1]), fminf(red[2], red[3]));
      mx = fmaxf(fmaxf(red[4], red[5]), fmaxf(red[6], red[7]));
      atomicMin(mm + 0, f2ord(mn));
      atomicMax(mm + 1, f2ord(mx));
    }
  }
  if (EPI == 2){
    if (tid < SEP) lh[tid] = 0u;
    __syncthreads();
    const float mnv = ord2f(mm[0]);
    const float mxv = ord2f(mm[1]);
    const float interval = (mxv - mnv) / 64.0f;
    #pragma unroll
    for (int m = 0; m < 4; ++m)
      #pragma unroll
      for (int n = 0; n < 4; ++n)
        #pragma unroll
        for (int q = 0; q < 4; ++q)
          atomicAdd(&lh[bin_of(acc[m][n][q], mnv, interval)], 1u);
    __syncthreads();
    if (tid < SEP){ unsigned c = lh[tid]; if (c) atomicAdd(hist + tid, c); }
  }
}

// ---------- tail histogram + analytic finalize (1 block). flag: 0 = done ----------
__global__ __launch_bounds__(256) void finalize2_kernel(const unsigned* __restrict__ mm,
                                                        const unsigned* __restrict__ lcnt,
                                                        const unsigned* __restrict__ viol,
                                                        const float* __restrict__ vex,
                                                        const float* __restrict__ W,
                                                        unsigned* __restrict__ flag,
                                                        float* __restrict__ out){
  __shared__ unsigned h[SEP];
  __shared__ unsigned okf;
  const int tid = threadIdx.x;
  if (tid < SEP) h[tid] = 0u;
  __syncthreads();
  const float mnv = ord2f(mm[0]);
  const float mxv = ord2f(mm[1]);
  const float interval = (mxv - mnv) / 64.0f;
  const unsigned cnt = lcnt[0];
  const unsigned n = cnt > LIST_CAP ? LIST_CAP : cnt;
  for (unsigned i = tid; i < n; i += 256u)
    atomicAdd(&h[bin_of(vex[i], mnv, interval)], 1u);
  __syncthreads();
  if (tid == 0){
    // Monotone binning: bins strictly outside [bin(-TEXACT), bin(TEXACT)] hold ONLY
    // candidate values (guarded model-error bound), so their counts here are exact.
    const int bLO = bin_of(-TEXACT, mnv, interval);
    const int bHI = bin_of( TEXACT, mnv, interval);
    bool ok = (cnt <= LIST_CAP) && (viol[0] == 0u) && (bLO >= 3) && (bHI <= 60) && (bLO < bHI)
              && (h[bLO - 1] >= 30u) && (h[bHI + 1] >= 30u);
    okf = ok ? 1u : 0u;
    if (ok) flag[0] = 0u;                                // analytic path done
  }
  __syncthreads();
  if (!okf) return;                                      // flag stays 1 -> exact fallback
  if (tid < 64){
    const int bLO = bin_of(-TEXACT, mnv, interval);
    const int bHI = bin_of( TEXACT, mnv, interval);
    float beta;
    if (tid < bLO || tid > bHI) beta = 1.f / (1.f + expf(-(float)h[tid]));
    else beta = 1.0f;                                    // count >= 30 -> f32 sigmoid == 1.0f
    float p = beta * W[tid];
    #pragma unroll
    for (int off = 32; off; off >>= 1) p += __shfl_down(p, off);
    if (tid == 0) out[0] = 1.f / (1.f + expf(-p));
  }
}

// ---------- fallback finalize: out = sigmoid( sum_j sigmoid(count_j) * W_j ) ----------
__global__ void fin_kernel(const unsigned* __restrict__ hist, const float* __restrict__ W,
                           const unsigned* __restrict__ flag, float* __restrict__ out){
  if (flag[0] == 0u) return;                             // finalize2 already wrote out
  int j = threadIdx.x;                                   // 64 threads = 1 wave
  float beta = 1.f / (1.f + expf(-(float)hist[j]));
  float p = beta * W[j];
  #pragma unroll
  for (int off = 32; off; off >>= 1) p += __shfl_down(p, off);
  if (j == 0) out[0] = 1.f / (1.f + expf(-p));
}

extern "C" void kernel_launch(void* const* d_in, const int* in_sizes, int n_in,
                              void* d_out, int out_size, void* d_ws, size_t ws_size,
                              hipStream_t stream){
  const float* cur  = (const float*)d_in[0];
  const float* prev = (const float*)d_in[1];
  const float* W    = (const float*)d_in[2];
  float* out = (float*)d_out;
  char* ws = (char*)d_ws;

  // ws layout
  unsigned short* cur2  = (unsigned short*)ws;                 // 12,582,912 B
  unsigned short* prev2 = (unsigned short*)(ws + 12582912);    // 12,582,912 B -> 25,165,824
  unsigned* ctl   = (unsigned*)(ws + 25165824);                // control block
  unsigned* mm    = ctl + 0;                                   // [min,max] ordered-u32
  unsigned* flag  = ctl + 2;
  unsigned* lcnt  = ctl + 3;
  unsigned* viol  = ctl + 4;
  unsigned* hist  = ctl + 5;                                   // 64 x u32 (fallback)
  unsigned* idxq  = (unsigned*)(ws + 25166592);                // 2 MiB packed candidates
  float*    vex   = (float*)(ws + 27263744);                   // 2 MiB exact values
  const size_t NEED_NEW = 29360896;                            // known to fit (r5-r9 ran)

  split_kernel<<<4096, 256, 0, stream>>>(cur, prev, cur2, prev2, ctl);

  if (ws_size >= NEED_NEW){
    // hi-only single-buffer GEMM + fused candidate spill/recompute; then hist+finalize
    gemm_det<<<4096, 256, 0, stream>>>(cur2, prev2, cur, prev, idxq, vex, lcnt, mm, viol);
    finalize2_kernel<<<1, 256, 0, stream>>>(mm, lcnt, viol, vex, W, flag, out);
    // guarded exact fallback (no-ops when flag == 0)
    gemm_kernel<0><<<4096, 256, 0, stream>>>(cur2, prev2, mm, hist, flag);
    gemm_kernel<2><<<4096, 256, 0, stream>>>(cur2, prev2, mm, hist, flag);
    fin_kernel<<<1, 64, 0, stream>>>(hist, W, flag, out);
  } else {
    // exact 2-pass path (flag stays 1 -> EPI0 + EPI2 + fin run fully)
    gemm_kernel<0><<<4096, 256, 0, stream>>>(cur2, prev2, mm, hist, flag);
    gemm_kernel<2><<<4096, 256, 0, stream>>>(cur2, prev2, mm, hist, flag);
    fin_kernel<<<1, 64, 0, stream>>>(hist, W, flag, out);
  }
}

// Round 12
// 188.486 us; speedup vs baseline: 1.1989x; 1.1782x over previous
//
#include <hip/hip_runtime.h>

typedef __attribute__((ext_vector_type(8))) short short8v;   // 8 bf16 (4 VGPRs)
typedef __attribute__((ext_vector_type(4))) float f32x4;     // MFMA accumulator

#define N_ROWS 8192
#define KSPLIT 768          // 3 x 256 (hi|lo|hi concatenation)
#define SEP 64
#define TDET 65.0f          // candidate-detection threshold on hi-only GEMM value
#define TEXACT 73.0f        // exact-bin boundary = TDET + guarded err bound
#define VTOL 5.5f           // |v_exact - dequant(v_hi)| guard
#define LIST_CAP 524288u

// ---------- helpers ----------
__device__ inline unsigned f2ord(float x){
  unsigned u = __float_as_uint(x);
  return (u & 0x80000000u) ? ~u : (u | 0x80000000u);   // monotone f32 -> u32
}
__device__ inline float ord2f(unsigned u){
  unsigned b = (u & 0x80000000u) ? (u & 0x7fffffffu) : ~u;
  return __uint_as_float(b);
}
__device__ inline unsigned short bf16rn(float x){
  unsigned b = __float_as_uint(x);
  unsigned r = (b + 0x7fffu + ((b >> 16) & 1u)) >> 16;  // round-to-nearest-even
  return (unsigned short)r;
}
__device__ inline void gload16(const void* g, void* l){
  __builtin_amdgcn_global_load_lds((const __attribute__((address_space(1))) void*)g,
                                   (__attribute__((address_space(3))) void*)l, 16, 0, 0);
}
__device__ inline int bin_of(float v, float mnv, float interval){
  float r = (v - mnv) / interval;                       // true division, like ref
  int b = (int)floorf(r);
  return b < 0 ? 0 : (b > 63 ? 63 : b);
}

// ---------- K0: split f32 -> bf16 hi/lo, K-concatenated; block 0 inits control ----------
__global__ void split_kernel(const float* __restrict__ cur, const float* __restrict__ prev,
                             unsigned short* __restrict__ cur2, unsigned short* __restrict__ prev2,
                             unsigned* __restrict__ ctl){
  if (blockIdx.x == 0){
    // ctl: [0]=min(ord) [1]=max(ord) [2]=flag [3]=lcnt [4]=viol [5]=done [6..69]=hist
    if (threadIdx.x == 0){
      ctl[0] = 0xFFFFFFFFu; ctl[1] = 0u; ctl[2] = 1u; ctl[3] = 0u; ctl[4] = 0u; ctl[5] = 0u;
    }
    if (threadIdx.x < 64) ctl[6 + threadIdx.x] = 0u;
  }
  int g = blockIdx.x * blockDim.x + threadIdx.x;         // 0 .. 2*524288-1
  int isB = (g >= (N_ROWS * 256 / 4)) ? 1 : 0;
  int t = g - isB * (N_ROWS * 256 / 4);
  const float4 v = ((const float4*)(isB ? prev : cur))[t];
  int row = t >> 6;                                      // 64 float4 per 256-col row
  int col = (t & 63) << 2;
  float xs[4] = {v.x, v.y, v.z, v.w};
  unsigned short h[4], l[4];
  #pragma unroll
  for (int j = 0; j < 4; ++j){
    unsigned short hb = bf16rn(xs[j]);
    float hf = __uint_as_float(((unsigned)hb) << 16);
    h[j] = hb;
    l[j] = bf16rn(xs[j] - hf);                           // residual capture
  }
  unsigned short* dst = isB ? prev2 : cur2;
  size_t base = (size_t)row * KSPLIT + col;
  uint2 hw, lw;
  hw.x = (unsigned)h[0] | ((unsigned)h[1] << 16); hw.y = (unsigned)h[2] | ((unsigned)h[3] << 16);
  lw.x = (unsigned)l[0] | ((unsigned)l[1] << 16); lw.y = (unsigned)l[2] | ((unsigned)l[3] << 16);
  *(uint2*)(dst + base) = hw;
  if (!isB){
    *(uint2*)(dst + base + 256) = lw;
    *(uint2*)(dst + base + 512) = hw;
  } else {
    *(uint2*)(dst + base + 256) = hw;
    *(uint2*)(dst + base + 512) = lw;
  }
}

// ---------- GEMM: 128x128 tile, 4 waves (2x2), 16x16x32 bf16 MFMA ----------
// (r6-benched 74us structure, restored verbatim)
// EPI 0: min/max only             (fallback pass 1; runs only when flag!=0)
// EPI 2: exact 64-bin histogram   (fallback pass 2; runs only when flag!=0)
// EPI 4: candidate spill (|v|>TDET -> packed u32), direct global, one atomic/wave
template<int EPI, int KSTEPS>
__global__ __launch_bounds__(256) void gemm_kernel(const unsigned short* __restrict__ A2,
                                                   const unsigned short* __restrict__ B2,
                                                   unsigned* __restrict__ mm,
                                                   unsigned* __restrict__ hist,
                                                   unsigned* __restrict__ idxq,
                                                   unsigned* __restrict__ lcnt,
                                                   const unsigned* __restrict__ flag){
  if (EPI == 0 || EPI == 2){
    if (flag[0] == 0u) return;                           // analytic path succeeded: no-op
  }
  __shared__ unsigned short As[128 * 32];
  __shared__ unsigned short Bs[128 * 32];

  const int tid  = threadIdx.x;
  const int lane = tid & 63;
  const int wave = tid >> 6;
  // XCD-aware bijective swizzle (4096 blocks = 8 XCDs x 512): neighbors share L2
  const int swz = ((blockIdx.x & 7) << 9) | (blockIdx.x >> 3);
  const int bm = swz >> 6;
  const int bn = swz & 63;
  const int wr = wave >> 1, wc = wave & 1;

  const size_t aBase = (size_t)bm * 128 * KSPLIT;
  const size_t bBase = (size_t)bn * 128 * KSPLIT;
  const int id0 = tid, id1 = tid + 256;                  // 512 x 16B chunks per tile
  const size_t aOff0 = aBase + (size_t)(id0 >> 2) * KSPLIT + (id0 & 3) * 8;
  const size_t aOff1 = aBase + (size_t)(id1 >> 2) * KSPLIT + (id1 & 3) * 8;
  const size_t bOff0 = bBase + (size_t)(id0 >> 2) * KSPLIT + (id0 & 3) * 8;
  const size_t bOff1 = bBase + (size_t)(id1 >> 2) * KSPLIT + (id1 & 3) * 8;

  f32x4 acc[4][4];
  #pragma unroll
  for (int m = 0; m < 4; ++m)
    #pragma unroll
    for (int n = 0; n < 4; ++n)
      acc[m][n] = (f32x4){0.f, 0.f, 0.f, 0.f};

  const int rsel = lane & 15;
  const int ksel = (lane >> 4) * 8;

  for (int ks = 0; ks < KSTEPS; ++ks){
    const int k0 = ks * 32;
    gload16(A2 + aOff0 + k0, As + id0 * 8);
    gload16(A2 + aOff1 + k0, As + id1 * 8);
    gload16(B2 + bOff0 + k0, Bs + id0 * 8);
    gload16(B2 + bOff1 + k0, Bs + id1 * 8);
    __syncthreads();
    short8v a[4], b[4];
    #pragma unroll
    for (int m = 0; m < 4; ++m)
      a[m] = *(const short8v*)(As + (wr * 64 + m * 16 + rsel) * 32 + ksel);
    #pragma unroll
    for (int n = 0; n < 4; ++n)
      b[n] = *(const short8v*)(Bs + (wc * 64 + n * 16 + rsel) * 32 + ksel);
    #pragma unroll
    for (int m = 0; m < 4; ++m)
      #pragma unroll
      for (int n = 0; n < 4; ++n)
        acc[m][n] = __builtin_amdgcn_mfma_f32_16x16x32_bf16(a[m], b[n], acc[m][n], 0, 0, 0);
    __syncthreads();
  }

  // epilogue scratch overlays (As/Bs dead after last barrier)
  float*    red = (float*)As;                            // 8 floats
  unsigned* lh  = (unsigned*)((char*)As + 64);           // 64 u32

  if (EPI == 0){
    float mn = 3.4e38f, mx = -3.4e38f;
    #pragma unroll
    for (int m = 0; m < 4; ++m)
      #pragma unroll
      for (int n = 0; n < 4; ++n)
        #pragma unroll
        for (int q = 0; q < 4; ++q){
          float v = acc[m][n][q];
          mn = fminf(mn, v); mx = fmaxf(mx, v);
        }
    #pragma unroll
    for (int off = 32; off; off >>= 1){
      mn = fminf(mn, __shfl_xor(mn, off));
      mx = fmaxf(mx, __shfl_xor(mx, off));
    }
    if (lane == 0){ red[wave] = mn; red[4 + wave] = mx; }
    __syncthreads();
    if (tid == 0){
      mn = fminf(fminf(red[0], red[1]), fminf(red[2], red[3]));
      mx = fmaxf(fmaxf(red[4], red[5]), fmaxf(red[6], red[7]));
      atomicMin(mm + 0, f2ord(mn));
      atomicMax(mm + 1, f2ord(mx));
    }
  }
  if (EPI == 2){
    if (tid < SEP) lh[tid] = 0u;
    __syncthreads();
    const float mnv = ord2f(mm[0]);
    const float mxv = ord2f(mm[1]);
    const float interval = (mxv - mnv) / 64.0f;
    #pragma unroll
    for (int m = 0; m < 4; ++m)
      #pragma unroll
      for (int n = 0; n < 4; ++n)
        #pragma unroll
        for (int q = 0; q < 4; ++q)
          atomicAdd(&lh[bin_of(acc[m][n][q], mnv, interval)], 1u);
    __syncthreads();
    if (tid < SEP){ unsigned c = lh[tid]; if (c) atomicAdd(hist + tid, c); }
  }
  if (EPI == 4){
    // pass 1: per-lane tail mask over the 64 accumulator values
    unsigned long long mask = 0ull;
    #pragma unroll
    for (int m = 0; m < 4; ++m)
      #pragma unroll
      for (int n = 0; n < 4; ++n)
        #pragma unroll
        for (int q = 0; q < 4; ++q){
          int b = (m * 4 + n) * 4 + q;
          if (fabsf(acc[m][n][q]) > TDET) mask |= (1ull << b);
        }
    int cnt = __popcll(mask);
    int pre = cnt;                                       // inclusive prefix over 64 lanes
    #pragma unroll
    for (int off = 1; off < 64; off <<= 1){
      int t = __shfl_up(pre, off);
      if (lane >= off) pre += t;
    }
    int tot = __shfl(pre, 63);                           // wave total
    int base = 0;
    if (lane == 63 && tot > 0) base = (int)atomicAdd(lcnt, (unsigned)tot);
    base = __shfl(base, 63);                             // ONE global atomic per wave
    if (mask){
      unsigned kk = (unsigned)(base + pre - cnt);
      #pragma unroll
      for (int m = 0; m < 4; ++m)
        #pragma unroll
        for (int n = 0; n < 4; ++n)
          #pragma unroll
          for (int q = 0; q < 4; ++q){
            int b = (m * 4 + n) * 4 + q;
            if ((mask >> b) & 1ull){
              float v = acc[m][n][q];
              // D layout (m89/m91-verified): row=(lane>>4)*4+q, col=lane&15
              int i = bm * 128 + wr * 64 + m * 16 + ((lane >> 4) << 2) + q;
              int j = bn * 128 + wc * 64 + n * 16 + (lane & 15);
              int e = (int)((v + 144.0f) * (1.0f / 4.5f));  // 6-bit quant, step 4.5
              e = e < 0 ? 0 : (e > 63 ? 63 : e);
              if (kk < LIST_CAP)
                idxq[kk] = ((unsigned)e << 26) | ((unsigned)i << 13) | (unsigned)j;
              ++kk;
            }
          }
    }
  }
}

// ---------- exact f32 recompute of candidates + last-block fused finalize ----------
__global__ __launch_bounds__(256) void recompute_kernel(const float* __restrict__ cur,
                                                        const float* __restrict__ prev,
                                                        const unsigned* __restrict__ idxq,
                                                        const unsigned* __restrict__ lcnt,
                                                        unsigned* __restrict__ mm,
                                                        unsigned* __restrict__ viol,
                                                        float* __restrict__ vex,
                                                        const float* __restrict__ W,
                                                        unsigned* __restrict__ flag,
                                                        float* __restrict__ out,
                                                        unsigned* __restrict__ done){
  const int lane = threadIdx.x & 63;
  const int w  = (blockIdx.x * blockDim.x + threadIdx.x) >> 6;
  const int nw = (gridDim.x * blockDim.x) >> 6;
  unsigned n = lcnt[0]; if (n > LIST_CAP) n = LIST_CAP;
  float wmn = 3.4e38f, wmx = -3.4e38f;
  bool any = false;
  for (unsigned c = w; c < n; c += (unsigned)nw){
    unsigned u = idxq[c];
    int i = (int)((u >> 13) & 8191u), j = (int)(u & 8191u);
    float4 a = ((const float4*)cur)[i * 64 + lane];      // wave reads 1KB contiguous
    float4 b = ((const float4*)prev)[j * 64 + lane];
    float s = a.x * b.x + a.y * b.y + a.z * b.z + a.w * b.w;
    #pragma unroll
    for (int off = 32; off; off >>= 1) s += __shfl_xor(s, off);
    if (lane == 0){
      vex[c] = s;
      float dq = ((float)(u >> 26) + 0.5f) * 4.5f - 144.0f;
      if (fabsf(s - dq) > VTOL) atomicAdd(viol, 1u);     // layout/index guard
    }
    wmn = fminf(wmn, s); wmx = fmaxf(wmx, s);
    any = true;
  }
  if (lane == 0 && any){
    atomicMin(mm + 0, f2ord(wmn));
    atomicMax(mm + 1, f2ord(wmx));
  }

  // ---- last-finishing block performs the finalize (saves 2 dispatches) ----
  __threadfence();                                       // release vex stores
  __shared__ unsigned lastf;
  if (threadIdx.x == 0)
    lastf = (atomicAdd(done, 1u) == gridDim.x - 1u) ? 1u : 0u;
  __syncthreads();
  if (!lastf) return;
  __threadfence();                                       // acquire other blocks' stores

  __shared__ unsigned h[SEP];
  __shared__ unsigned okf;
  const int tid = threadIdx.x;
  if (tid < SEP) h[tid] = 0u;
  __syncthreads();
  const float mnv = ord2f(mm[0]);
  const float mxv = ord2f(mm[1]);
  const float interval = (mxv - mnv) / 64.0f;
  const unsigned cnt = lcnt[0];
  const unsigned n2 = cnt > LIST_CAP ? LIST_CAP : cnt;
  for (unsigned i2 = tid; i2 < n2; i2 += 256u)
    atomicAdd(&h[bin_of(vex[i2], mnv, interval)], 1u);
  __syncthreads();
  if (tid == 0){
    // Monotone binning: bins strictly outside [bin(-TEXACT), bin(TEXACT)] hold ONLY
    // candidate values (guarded model-error bound), so their counts here are exact.
    const int bLO = bin_of(-TEXACT, mnv, interval);
    const int bHI = bin_of( TEXACT, mnv, interval);
    bool ok = (cnt <= LIST_CAP) && (viol[0] == 0u) && (bLO >= 3) && (bHI <= 60) && (bLO < bHI)
              && (h[bLO - 1] >= 30u) && (h[bHI + 1] >= 30u);
    okf = ok ? 1u : 0u;
    if (ok) flag[0] = 0u;                                // analytic path done
  }
  __syncthreads();
  if (!okf) return;                                      // flag stays 1 -> exact fallback
  if (tid < 64){
    const int bLO = bin_of(-TEXACT, mnv, interval);
    const int bHI = bin_of( TEXACT, mnv, interval);
    float beta;
    if (tid < bLO || tid > bHI) beta = 1.f / (1.f + expf(-(float)h[tid]));
    else beta = 1.0f;                                    // count >= 30 -> f32 sigmoid == 1.0f
    float p = beta * W[tid];
    #pragma unroll
    for (int off = 32; off; off >>= 1) p += __shfl_down(p, off);
    if (tid == 0) out[0] = 1.f / (1.f + expf(-p));
  }
}

// ---------- fallback finalize: out = sigmoid( sum_j sigmoid(count_j) * W_j ) ----------
__global__ void fin_kernel(const unsigned* __restrict__ hist, const float* __restrict__ W,
                           const unsigned* __restrict__ flag, float* __restrict__ out){
  if (flag[0] == 0u) return;                             // recompute finalize wrote out
  int j = threadIdx.x;                                   // 64 threads = 1 wave
  float beta = 1.f / (1.f + expf(-(float)hist[j]));
  float p = beta * W[j];
  #pragma unroll
  for (int off = 32; off; off >>= 1) p += __shfl_down(p, off);
  if (j == 0) out[0] = 1.f / (1.f + expf(-p));
}

extern "C" void kernel_launch(void* const* d_in, const int* in_sizes, int n_in,
                              void* d_out, int out_size, void* d_ws, size_t ws_size,
                              hipStream_t stream){
  const float* cur  = (const float*)d_in[0];
  const float* prev = (const float*)d_in[1];
  const float* W    = (const float*)d_in[2];
  float* out = (float*)d_out;
  char* ws = (char*)d_ws;

  // ws layout
  unsigned short* cur2  = (unsigned short*)ws;                 // 12,582,912 B
  unsigned short* prev2 = (unsigned short*)(ws + 12582912);    // 12,582,912 B -> 25,165,824
  unsigned* ctl   = (unsigned*)(ws + 25165824);                // control block
  unsigned* mm    = ctl + 0;                                   // [min,max] ordered-u32
  unsigned* flag  = ctl + 2;
  unsigned* lcnt  = ctl + 3;
  unsigned* viol  = ctl + 4;
  unsigned* done  = ctl + 5;
  unsigned* hist  = ctl + 6;                                   // 64 x u32 (fallback)
  unsigned* idxq  = (unsigned*)(ws + 25166592);                // 2 MiB packed candidates
  float*    vex   = (float*)(ws + 27263744);                   // 2 MiB exact values
  const size_t NEED_NEW = 29360896;                            // known to fit (r5-r10 ran)

  split_kernel<<<4096, 256, 0, stream>>>(cur, prev, cur2, prev2, ctl);

  if (ws_size >= NEED_NEW){
    // hi-only GEMM (K=256) + direct candidate spill (r6-verified, 74us);
    // recompute exact tails + last-block finalize; guarded exact fallback
    gemm_kernel<4, 8><<<4096, 256, 0, stream>>>(cur2, prev2, mm, hist, idxq, lcnt, flag);
    recompute_kernel<<<256, 256, 0, stream>>>(cur, prev, idxq, lcnt, mm, viol, vex,
                                              W, flag, out, done);
    gemm_kernel<0, 24><<<4096, 256, 0, stream>>>(cur2, prev2, mm, hist, idxq, lcnt, flag);
    gemm_kernel<2, 24><<<4096, 256, 0, stream>>>(cur2, prev2, mm, hist, idxq, lcnt, flag);
    fin_kernel<<<1, 64, 0, stream>>>(hist, W, flag, out);
  } else {
    // exact 2-pass path (flag stays 1 -> EPI0 + EPI2 + fin run fully)
    gemm_kernel<0, 24><<<4096, 256, 0, stream>>>(cur2, prev2, mm, hist, idxq, lcnt, flag);
    gemm_kernel<2, 24><<<4096, 256, 0, stream>>>(cur2, prev2, mm, hist, idxq, lcnt, flag);
    fin_kernel<<<1, 64, 0, stream>>>(hist, W, flag, out);
  }
}

// Round 13
// 182.085 us; speedup vs baseline: 1.2410x; 1.0352x over previous
//
#include <hip/hip_runtime.h>

typedef __attribute__((ext_vector_type(8))) short short8v;   // 8 bf16 (4 VGPRs)
typedef __attribute__((ext_vector_type(4))) float f32x4;     // MFMA accumulator

#define N_ROWS 8192
#define KS2 512             // [hi | lo] concatenation, row stride 512
#define SEP 64
#define TDET 65.0f          // candidate-detection threshold on hi-only GEMM value
#define TEXACT 73.0f        // exact-bin boundary = TDET + guarded err bound
#define VTOL 5.5f           // |v_exact - dequant(v_hi)| guard
#define LIST_CAP 524288u

// ---------- helpers ----------
__device__ inline unsigned f2ord(float x){
  unsigned u = __float_as_uint(x);
  return (u & 0x80000000u) ? ~u : (u | 0x80000000u);   // monotone f32 -> u32
}
__device__ inline float ord2f(unsigned u){
  unsigned b = (u & 0x80000000u) ? (u & 0x7fffffffu) : ~u;
  return __uint_as_float(b);
}
__device__ inline unsigned short bf16rn(float x){
  unsigned b = __float_as_uint(x);
  unsigned r = (b + 0x7fffu + ((b >> 16) & 1u)) >> 16;  // round-to-nearest-even
  return (unsigned short)r;
}
__device__ inline void gload16(const void* g, void* l){
  __builtin_amdgcn_global_load_lds((const __attribute__((address_space(1))) void*)g,
                                   (__attribute__((address_space(3))) void*)l, 16, 0, 0);
}
__device__ inline int bin_of(float v, float mnv, float interval){
  float r = (v - mnv) / interval;                       // true division, like ref
  int b = (int)floorf(r);
  return b < 0 ? 0 : (b > 63 ? 63 : b);
}

// ---------- K0: split f32 -> bf16 [hi | lo] (stride 512); block 0 inits control ----------
__global__ void split_kernel(const float* __restrict__ cur, const float* __restrict__ prev,
                             unsigned short* __restrict__ cur2, unsigned short* __restrict__ prev2,
                             unsigned* __restrict__ ctl){
  if (blockIdx.x == 0){
    // ctl: [0]=min(ord) [1]=max(ord) [2]=flag [3]=lcnt [4]=viol [5]=done [6..69]=hist
    if (threadIdx.x == 0){
      ctl[0] = 0xFFFFFFFFu; ctl[1] = 0u; ctl[2] = 1u; ctl[3] = 0u; ctl[4] = 0u; ctl[5] = 0u;
    }
    if (threadIdx.x < 64) ctl[6 + threadIdx.x] = 0u;
  }
  int g = blockIdx.x * blockDim.x + threadIdx.x;         // 0 .. 2*524288-1
  int isB = (g >= (N_ROWS * 256 / 4)) ? 1 : 0;
  int t = g - isB * (N_ROWS * 256 / 4);
  const float4 v = ((const float4*)(isB ? prev : cur))[t];
  int row = t >> 6;                                      // 64 float4 per 256-col row
  int col = (t & 63) << 2;
  float xs[4] = {v.x, v.y, v.z, v.w};
  unsigned short h[4], l[4];
  #pragma unroll
  for (int j = 0; j < 4; ++j){
    unsigned short hb = bf16rn(xs[j]);
    float hf = __uint_as_float(((unsigned)hb) << 16);
    h[j] = hb;
    l[j] = bf16rn(xs[j] - hf);                           // residual capture
  }
  unsigned short* dst = isB ? prev2 : cur2;
  size_t base = (size_t)row * KS2 + col;
  uint2 hw, lw;
  hw.x = (unsigned)h[0] | ((unsigned)h[1] << 16); hw.y = (unsigned)h[2] | ((unsigned)h[3] << 16);
  lw.x = (unsigned)l[0] | ((unsigned)l[1] << 16); lw.y = (unsigned)l[2] | ((unsigned)l[3] << 16);
  *(uint2*)(dst + base) = hw;                            // hi at cols [0,256)
  *(uint2*)(dst + base + 256) = lw;                      // lo at cols [256,512)
}

// ---------- detection GEMM: 128x128, 4 waves (2x2), hi-only K=256 ----------
// 4 staged steps; each stages TWO BK=32 buffer-pairs, 1 barrier, 32 MFMA/wave, 1 barrier
// (halves the vmcnt(0)+barrier drains vs the r6 8-step loop; row stride in each
// buffer stays 64 B so LDS bank behavior is unchanged).
// Epilogue: r6-verbatim EPI4 direct candidate spill, one global atomic per wave.
__global__ __launch_bounds__(256) void gemm_det(const unsigned short* __restrict__ A2,
                                                const unsigned short* __restrict__ B2,
                                                unsigned* __restrict__ idxq,
                                                unsigned* __restrict__ lcnt){
  __shared__ unsigned short As[2][128 * 32];             // 16 KB
  __shared__ unsigned short Bs[2][128 * 32];             // 16 KB (32 KB total)

  const int tid  = threadIdx.x;
  const int lane = tid & 63;
  const int wave = tid >> 6;
  // XCD-aware bijective swizzle (4096 blocks = 8 XCDs x 512): neighbors share L2
  const int swz = ((blockIdx.x & 7) << 9) | (blockIdx.x >> 3);
  const int bm = swz >> 6;
  const int bn = swz & 63;
  const int wr = wave >> 1, wc = wave & 1;

  const size_t aBase = (size_t)bm * 128 * KS2;
  const size_t bBase = (size_t)bn * 128 * KS2;
  const int id0 = tid, id1 = tid + 256;                  // 512 x 16B chunks per tile
  const size_t aOff0 = aBase + (size_t)(id0 >> 2) * KS2 + (id0 & 3) * 8;
  const size_t aOff1 = aBase + (size_t)(id1 >> 2) * KS2 + (id1 & 3) * 8;
  const size_t bOff0 = bBase + (size_t)(id0 >> 2) * KS2 + (id0 & 3) * 8;
  const size_t bOff1 = bBase + (size_t)(id1 >> 2) * KS2 + (id1 & 3) * 8;

  f32x4 acc[4][4];
  #pragma unroll
  for (int m = 0; m < 4; ++m)
    #pragma unroll
    for (int n = 0; n < 4; ++n)
      acc[m][n] = (f32x4){0.f, 0.f, 0.f, 0.f};

  const int rsel = lane & 15;
  const int ksel = (lane >> 4) * 8;

  for (int st = 0; st < 4; ++st){
    const int k0 = st * 64;
    gload16(A2 + aOff0 + k0,      &As[0][id0 * 8]);
    gload16(A2 + aOff1 + k0,      &As[0][id1 * 8]);
    gload16(B2 + bOff0 + k0,      &Bs[0][id0 * 8]);
    gload16(B2 + bOff1 + k0,      &Bs[0][id1 * 8]);
    gload16(A2 + aOff0 + k0 + 32, &As[1][id0 * 8]);
    gload16(A2 + aOff1 + k0 + 32, &As[1][id1 * 8]);
    gload16(B2 + bOff0 + k0 + 32, &Bs[1][id0 * 8]);
    gload16(B2 + bOff1 + k0 + 32, &Bs[1][id1 * 8]);
    __syncthreads();
    #pragma unroll
    for (int p = 0; p < 2; ++p){
      short8v a[4], b[4];
      #pragma unroll
      for (int m = 0; m < 4; ++m)
        a[m] = *(const short8v*)(&As[p][(wr * 64 + m * 16 + rsel) * 32 + ksel]);
      #pragma unroll
      for (int n = 0; n < 4; ++n)
        b[n] = *(const short8v*)(&Bs[p][(wc * 64 + n * 16 + rsel) * 32 + ksel]);
      #pragma unroll
      for (int m = 0; m < 4; ++m)
        #pragma unroll
        for (int n = 0; n < 4; ++n)
          acc[m][n] = __builtin_amdgcn_mfma_f32_16x16x32_bf16(a[m], b[n], acc[m][n], 0, 0, 0);
    }
    __syncthreads();
  }

  // ---- EPI4 epilogue (r6-verbatim): per-lane tail mask, one global atomic per wave ----
  unsigned long long mask = 0ull;
  #pragma unroll
  for (int m = 0; m < 4; ++m)
    #pragma unroll
    for (int n = 0; n < 4; ++n)
      #pragma unroll
      for (int q = 0; q < 4; ++q){
        int b = (m * 4 + n) * 4 + q;
        if (fabsf(acc[m][n][q]) > TDET) mask |= (1ull << b);
      }
  int cnt = __popcll(mask);
  int pre = cnt;                                         // inclusive prefix over 64 lanes
  #pragma unroll
  for (int off = 1; off < 64; off <<= 1){
    int t = __shfl_up(pre, off);
    if (lane >= off) pre += t;
  }
  int tot = __shfl(pre, 63);                             // wave total
  int base = 0;
  if (lane == 63 && tot > 0) base = (int)atomicAdd(lcnt, (unsigned)tot);
  base = __shfl(base, 63);                               // ONE global atomic per wave
  if (mask){
    unsigned kk = (unsigned)(base + pre - cnt);
    #pragma unroll
    for (int m = 0; m < 4; ++m)
      #pragma unroll
      for (int n = 0; n < 4; ++n)
        #pragma unroll
        for (int q = 0; q < 4; ++q){
          int b = (m * 4 + n) * 4 + q;
          if ((mask >> b) & 1ull){
            float v = acc[m][n][q];
            // D layout (m89/m91-verified): row=(lane>>4)*4+q, col=lane&15
            int i = bm * 128 + wr * 64 + m * 16 + ((lane >> 4) << 2) + q;
            int j = bn * 128 + wc * 64 + n * 16 + (lane & 15);
            int e = (int)((v + 144.0f) * (1.0f / 4.5f));  // 6-bit quant, step 4.5
            e = e < 0 ? 0 : (e > 63 ? 63 : e);
            if (kk < LIST_CAP)
              idxq[kk] = ((unsigned)e << 26) | ((unsigned)i << 13) | (unsigned)j;
            ++kk;
          }
        }
  }
}

// ---------- fallback GEMM (exact): 128x128, 24 K-steps over [hi|lo] via k0 remap ----------
// seg 0 (ks 0-7):  A hi(kk) * B hi(kk)      -> hi*hi
// seg 1 (ks 8-15): A lo(256+kk) * B hi(kk)  -> lo*hi
// seg 2 (ks16-23): A hi(kk) * B lo(256+kk)  -> hi*lo
// Same three product terms as the old [hi|lo|hi] layout. No-op when flag==0.
template<int EPI>
__global__ __launch_bounds__(256) void gemm_kernel(const unsigned short* __restrict__ A2,
                                                   const unsigned short* __restrict__ B2,
                                                   unsigned* __restrict__ mm,
                                                   unsigned* __restrict__ hist,
                                                   const unsigned* __restrict__ flag){
  if (flag[0] == 0u) return;                             // analytic path succeeded: no-op
  __shared__ unsigned short As[128 * 32];
  __shared__ unsigned short Bs[128 * 32];

  const int tid  = threadIdx.x;
  const int lane = tid & 63;
  const int wave = tid >> 6;
  const int swz = ((blockIdx.x & 7) << 9) | (blockIdx.x >> 3);
  const int bm = swz >> 6;
  const int bn = swz & 63;
  const int wr = wave >> 1, wc = wave & 1;

  const size_t aBase = (size_t)bm * 128 * KS2;
  const size_t bBase = (size_t)bn * 128 * KS2;
  const int id0 = tid, id1 = tid + 256;
  const size_t aOff0 = aBase + (size_t)(id0 >> 2) * KS2 + (id0 & 3) * 8;
  const size_t aOff1 = aBase + (size_t)(id1 >> 2) * KS2 + (id1 & 3) * 8;
  const size_t bOff0 = bBase + (size_t)(id0 >> 2) * KS2 + (id0 & 3) * 8;
  const size_t bOff1 = bBase + (size_t)(id1 >> 2) * KS2 + (id1 & 3) * 8;

  f32x4 acc[4][4];
  #pragma unroll
  for (int m = 0; m < 4; ++m)
    #pragma unroll
    for (int n = 0; n < 4; ++n)
      acc[m][n] = (f32x4){0.f, 0.f, 0.f, 0.f};

  const int rsel = lane & 15;
  const int ksel = (lane >> 4) * 8;

  for (int ks = 0; ks < 24; ++ks){
    const int seg = ks >> 3;
    const int kk  = (ks & 7) * 32;
    const int aK0 = (seg == 1) ? 256 + kk : kk;
    const int bK0 = (seg == 2) ? 256 + kk : kk;
    gload16(A2 + aOff0 + aK0, As + id0 * 8);
    gload16(A2 + aOff1 + aK0, As + id1 * 8);
    gload16(B2 + bOff0 + bK0, Bs + id0 * 8);
    gload16(B2 + bOff1 + bK0, Bs + id1 * 8);
    __syncthreads();
    short8v a[4], b[4];
    #pragma unroll
    for (int m = 0; m < 4; ++m)
      a[m] = *(const short8v*)(As + (wr * 64 + m * 16 + rsel) * 32 + ksel);
    #pragma unroll
    for (int n = 0; n < 4; ++n)
      b[n] = *(const short8v*)(Bs + (wc * 64 + n * 16 + rsel) * 32 + ksel);
    #pragma unroll
    for (int m = 0; m < 4; ++m)
      #pragma unroll
      for (int n = 0; n < 4; ++n)
        acc[m][n] = __builtin_amdgcn_mfma_f32_16x16x32_bf16(a[m], b[n], acc[m][n], 0, 0, 0);
    __syncthreads();
  }

  float*    red = (float*)As;                            // epilogue overlays (As dead)
  unsigned* lh  = (unsigned*)((char*)As + 64);

  if (EPI == 0){
    float mn = 3.4e38f, mx = -3.4e38f;
    #pragma unroll
    for (int m = 0; m < 4; ++m)
      #pragma unroll
      for (int n = 0; n < 4; ++n)
        #pragma unroll
        for (int q = 0; q < 4; ++q){
          float v = acc[m][n][q];
          mn = fminf(mn, v); mx = fmaxf(mx, v);
        }
    #pragma unroll
    for (int off = 32; off; off >>= 1){
      mn = fminf(mn, __shfl_xor(mn, off));
      mx = fmaxf(mx, __shfl_xor(mx, off));
    }
    if (lane == 0){ red[wave] = mn; red[4 + wave] = mx; }
    __syncthreads();
    if (tid == 0){
      mn = fminf(fminf(red[0], red[1]), fminf(red[2], red[3]));
      mx = fmaxf(fmaxf(red[4], red[5]), fmaxf(red[6], red[7]));
      atomicMin(mm + 0, f2ord(mn));
      atomicMax(mm + 1, f2ord(mx));
    }
  }
  if (EPI == 2){
    if (tid < SEP) lh[tid] = 0u;
    __syncthreads();
    const float mnv = ord2f(mm[0]);
    const float mxv = ord2f(mm[1]);
    const float interval = (mxv - mnv) / 64.0f;
    #pragma unroll
    for (int m = 0; m < 4; ++m)
      #pragma unroll
      for (int n = 0; n < 4; ++n)
        #pragma unroll
        for (int q = 0; q < 4; ++q)
          atomicAdd(&lh[bin_of(acc[m][n][q], mnv, interval)], 1u);
    __syncthreads();
    if (tid < SEP){ unsigned c = lh[tid]; if (c) atomicAdd(hist + tid, c); }
  }
}

// ---------- exact f32 recompute of candidates + last-block fused finalize ----------
__global__ __launch_bounds__(256) void recompute_kernel(const float* __restrict__ cur,
                                                        const float* __restrict__ prev,
                                                        const unsigned* __restrict__ idxq,
                                                        const unsigned* __restrict__ lcnt,
                                                        unsigned* __restrict__ mm,
                                                        unsigned* __restrict__ viol,
                                                        float* __restrict__ vex,
                                                        const float* __restrict__ W,
                                                        unsigned* __restrict__ flag,
                                                        float* __restrict__ out,
                                                        unsigned* __restrict__ done){
  const int lane = threadIdx.x & 63;
  const int w  = (blockIdx.x * blockDim.x + threadIdx.x) >> 6;
  const int nw = (gridDim.x * blockDim.x) >> 6;
  unsigned n = lcnt[0]; if (n > LIST_CAP) n = LIST_CAP;
  float wmn = 3.4e38f, wmx = -3.4e38f;
  bool any = false;
  for (unsigned c = w; c < n; c += (unsigned)nw){
    unsigned u = idxq[c];
    int i = (int)((u >> 13) & 8191u), j = (int)(u & 8191u);
    float4 a = ((const float4*)cur)[i * 64 + lane];      // wave reads 1KB contiguous
    float4 b = ((const float4*)prev)[j * 64 + lane];
    float s = a.x * b.x + a.y * b.y + a.z * b.z + a.w * b.w;
    #pragma unroll
    for (int off = 32; off; off >>= 1) s += __shfl_xor(s, off);
    if (lane == 0){
      vex[c] = s;
      float dq = ((float)(u >> 26) + 0.5f) * 4.5f - 144.0f;
      if (fabsf(s - dq) > VTOL) atomicAdd(viol, 1u);     // layout/index guard
    }
    wmn = fminf(wmn, s); wmx = fmaxf(wmx, s);
    any = true;
  }
  if (lane == 0 && any){
    atomicMin(mm + 0, f2ord(wmn));
    atomicMax(mm + 1, f2ord(wmx));
  }

  // ---- last-finishing block performs the finalize (saves 2 dispatches) ----
  __threadfence();                                       // release vex stores
  __shared__ unsigned lastf;
  if (threadIdx.x == 0)
    lastf = (atomicAdd(done, 1u) == gridDim.x - 1u) ? 1u : 0u;
  __syncthreads();
  if (!lastf) return;
  __threadfence();                                       // acquire other blocks' stores

  __shared__ unsigned h[SEP];
  __shared__ unsigned okf;
  const int tid = threadIdx.x;
  if (tid < SEP) h[tid] = 0u;
  __syncthreads();
  const float mnv = ord2f(mm[0]);
  const float mxv = ord2f(mm[1]);
  const float interval = (mxv - mnv) / 64.0f;
  const unsigned cnt = lcnt[0];
  const unsigned n2 = cnt > LIST_CAP ? LIST_CAP : cnt;
  for (unsigned i2 = tid; i2 < n2; i2 += 256u)
    atomicAdd(&h[bin_of(vex[i2], mnv, interval)], 1u);
  __syncthreads();
  if (tid == 0){
    // Monotone binning: bins strictly outside [bin(-TEXACT), bin(TEXACT)] hold ONLY
    // candidate values (guarded model-error bound), so their counts here are exact.
    const int bLO = bin_of(-TEXACT, mnv, interval);
    const int bHI = bin_of( TEXACT, mnv, interval);
    bool ok = (cnt <= LIST_CAP) && (viol[0] == 0u) && (bLO >= 3) && (bHI <= 60) && (bLO < bHI)
              && (h[bLO - 1] >= 30u) && (h[bHI + 1] >= 30u);
    okf = ok ? 1u : 0u;
    if (ok) flag[0] = 0u;                                // analytic path done
  }
  __syncthreads();
  if (!okf) return;                                      // flag stays 1 -> exact fallback
  if (tid < 64){
    const int bLO = bin_of(-TEXACT, mnv, interval);
    const int bHI = bin_of( TEXACT, mnv, interval);
    float beta;
    if (tid < bLO || tid > bHI) beta = 1.f / (1.f + expf(-(float)h[tid]));
    else beta = 1.0f;                                    // count >= 30 -> f32 sigmoid == 1.0f
    float p = beta * W[tid];
    #pragma unroll
    for (int off = 32; off; off >>= 1) p += __shfl_down(p, off);
    if (tid == 0) out[0] = 1.f / (1.f + expf(-p));
  }
}

// ---------- fallback finalize: out = sigmoid( sum_j sigmoid(count_j) * W_j ) ----------
__global__ void fin_kernel(const unsigned* __restrict__ hist, const float* __restrict__ W,
                           const unsigned* __restrict__ flag, float* __restrict__ out){
  if (flag[0] == 0u) return;                             // recompute finalize wrote out
  int j = threadIdx.x;                                   // 64 threads = 1 wave
  float beta = 1.f / (1.f + expf(-(float)hist[j]));
  float p = beta * W[j];
  #pragma unroll
  for (int off = 32; off; off >>= 1) p += __shfl_down(p, off);
  if (j == 0) out[0] = 1.f / (1.f + expf(-p));
}

extern "C" void kernel_launch(void* const* d_in, const int* in_sizes, int n_in,
                              void* d_out, int out_size, void* d_ws, size_t ws_size,
                              hipStream_t stream){
  const float* cur  = (const float*)d_in[0];
  const float* prev = (const float*)d_in[1];
  const float* W    = (const float*)d_in[2];
  float* out = (float*)d_out;
  char* ws = (char*)d_ws;

  // ws layout ([hi|lo] packing shrinks everything; well under the known-good 29.4 MB)
  unsigned short* cur2  = (unsigned short*)ws;                 // 8,388,608 B
  unsigned short* prev2 = (unsigned short*)(ws + 8388608);     // 8,388,608 B -> 16,777,216
  unsigned* ctl   = (unsigned*)(ws + 16777216);                // control block (512 B)
  unsigned* mm    = ctl + 0;                                   // [min,max] ordered-u32
  unsigned* flag  = ctl + 2;
  unsigned* lcnt  = ctl + 3;
  unsigned* viol  = ctl + 4;
  unsigned* done  = ctl + 5;
  unsigned* hist  = ctl + 6;                                   // 64 x u32 (fallback)
  unsigned* idxq  = (unsigned*)(ws + 16777728);                // 2 MiB packed candidates
  float*    vex   = (float*)(ws + 18874880);                   // 2 MiB exact values
  const size_t NEED_NEW = 20972032;                            // < 29,360,896 known to fit

  split_kernel<<<4096, 256, 0, stream>>>(cur, prev, cur2, prev2, ctl);

  if (ws_size >= NEED_NEW){
    // hi-only GEMM (4 staged steps x 2 sub-steps) + direct candidate spill;
    // recompute exact tails + last-block finalize; guarded exact fallback
    gemm_det<<<4096, 256, 0, stream>>>(cur2, prev2, idxq, lcnt);
    recompute_kernel<<<256, 256, 0, stream>>>(cur, prev, idxq, lcnt, mm, viol, vex,
                                              W, flag, out, done);
    gemm_kernel<0><<<4096, 256, 0, stream>>>(cur2, prev2, mm, hist, flag);
    gemm_kernel<2><<<4096, 256, 0, stream>>>(cur2, prev2, mm, hist, flag);
    fin_kernel<<<1, 64, 0, stream>>>(hist, W, flag, out);
  } else {
    // exact 2-pass path (flag stays 1 -> EPI0 + EPI2 + fin run fully)
    gemm_kernel<0><<<4096, 256, 0, stream>>>(cur2, prev2, mm, hist, flag);
    gemm_kernel<2><<<4096, 256, 0, stream>>>(cur2, prev2, mm, hist, flag);
    fin_kernel<<<1, 64, 0, stream>>>(hist, W, flag, out);
  }
}